// Round 1
// baseline (13954.608 us; speedup 1.0000x reference)
//
#include <hip/hip_runtime.h>

#define TT 168
#define HH 64
#define GG 256   // 4*HH gates
#define DD 7
#define NS 8     // samples per block
#define BB 8192

__device__ __forceinline__ float sig_(float v) {
    return 1.0f / (1.0f + __expf(-v));
}
__device__ __forceinline__ float th_(float v) {
    // tanh(v) = 1 - 2/(exp(2v)+1); saturates correctly for |v| large
    return 1.0f - 2.0f / (__expf(2.0f * v) + 1.0f);
}

#define FMA8(LO, HI, W)                                                     \
    acc[0] = fmaf((LO).x, (W), acc[0]); acc[1] = fmaf((LO).y, (W), acc[1]); \
    acc[2] = fmaf((LO).z, (W), acc[2]); acc[3] = fmaf((LO).w, (W), acc[3]); \
    acc[4] = fmaf((HI).x, (W), acc[4]); acc[5] = fmaf((HI).y, (W), acc[5]); \
    acc[6] = fmaf((HI).z, (W), acc[6]); acc[7] = fmaf((HI).w, (W), acc[7]);

__global__ __launch_bounds__(256, 2)
void weather_lstm_fused(const float* __restrict__ x,
                        const float* __restrict__ w_ih0, const float* __restrict__ w_hh0,
                        const float* __restrict__ b_ih0, const float* __restrict__ b_hh0,
                        const float* __restrict__ w_ih1, const float* __restrict__ w_hh1,
                        const float* __restrict__ b_ih1, const float* __restrict__ b_hh1,
                        const float* __restrict__ fc_w, const float* __restrict__ fc_b,
                        float* __restrict__ out)
{
    __shared__ __align__(16) float xbuf[NS][8];       // x_t, padded to 8
    __shared__ __align__(16) float h1buf[HH][NS];     // layer0 hidden state
    __shared__ __align__(16) float h2buf[HH][NS];     // layer1 hidden state
    __shared__ __align__(16) float gbuf[GG][NS];      // raw gate pre-activations

    const int g  = threadIdx.x;          // gate index 0..255
    const int s0 = blockIdx.x * NS;      // first sample of this block

    // ---- weights resident in VGPRs (199 regs/thread) ----
    float wih0[DD], whh0[HH], wih1[HH], whh1[HH];
#pragma unroll
    for (int d = 0; d < DD; ++d) wih0[d] = w_ih0[g * DD + d];
#pragma unroll
    for (int j = 0; j < HH; ++j) whh0[j] = w_hh0[g * HH + j];
#pragma unroll
    for (int j = 0; j < HH; ++j) wih1[j] = w_ih1[g * HH + j];
#pragma unroll
    for (int j = 0; j < HH; ++j) whh1[j] = w_hh1[g * HH + j];
    const float bias0 = b_ih0[g] + b_hh0[g];
    const float bias1 = b_ih1[g] + b_hh1[g];

    // zero hidden state (HH*NS = 512 floats per buffer, 2 per thread)
    ((float*)h1buf)[g]      = 0.0f;
    ((float*)h1buf)[g + GG] = 0.0f;
    ((float*)h2buf)[g]      = 0.0f;
    ((float*)h2buf)[g + GG] = 0.0f;

    // this thread's state-update assignment: hidden unit ju, samples su, su+1
    const int ju = g >> 2;
    const int su = (g & 3) * 2;
    float c1a = 0.0f, c1b = 0.0f, c2a = 0.0f, c2b = 0.0f;

    for (int t = 0; t < TT; ++t) {
        // ---- stage x_t into LDS (56 threads) ----
        if (g < NS * DD) {
            const int s = g / DD, d = g - s * DD;
            xbuf[s][d] = x[((size_t)(s0 + s) * TT + t) * DD + d];
        }
        __syncthreads();   // x ready; h1buf/h2buf from t-1 ready

        float acc[NS];

        // ================= Phase A: layer-0 gates =================
#pragma unroll
        for (int s = 0; s < NS; ++s) acc[s] = bias0;
#pragma unroll
        for (int d = 0; d < DD; ++d) {
            const float w = wih0[d];
#pragma unroll
            for (int s = 0; s < NS; ++s) acc[s] = fmaf(xbuf[s][d], w, acc[s]);
        }
#pragma unroll
        for (int j = 0; j < HH; ++j) {
            const float4 lo = *(const float4*)(&h1buf[j][0]);
            const float4 hi = *(const float4*)(&h1buf[j][4]);
            const float w = whh0[j];
            FMA8(lo, hi, w)
        }
        *(float4*)(&gbuf[g][0]) = make_float4(acc[0], acc[1], acc[2], acc[3]);
        *(float4*)(&gbuf[g][4]) = make_float4(acc[4], acc[5], acc[6], acc[7]);
        __syncthreads();

        // ---- layer-0 state update (all 256 threads, 2 slots each) ----
        {
            const float i0 = sig_(gbuf[ju][su]),          i1 = sig_(gbuf[ju][su + 1]);
            const float f0 = sig_(gbuf[HH + ju][su]),     f1 = sig_(gbuf[HH + ju][su + 1]);
            const float g0 = th_(gbuf[2 * HH + ju][su]),  g1 = th_(gbuf[2 * HH + ju][su + 1]);
            const float o0 = sig_(gbuf[3 * HH + ju][su]), o1 = sig_(gbuf[3 * HH + ju][su + 1]);
            c1a = f0 * c1a + i0 * g0;
            c1b = f1 * c1b + i1 * g1;
            h1buf[ju][su]     = o0 * th_(c1a);
            h1buf[ju][su + 1] = o1 * th_(c1b);
        }
        __syncthreads();   // new h1 visible

        // ================= Phase B: layer-1 gates =================
#pragma unroll
        for (int s = 0; s < NS; ++s) acc[s] = bias1;
#pragma unroll
        for (int j = 0; j < HH; ++j) {
            const float4 lo = *(const float4*)(&h1buf[j][0]);
            const float4 hi = *(const float4*)(&h1buf[j][4]);
            const float w = wih1[j];
            FMA8(lo, hi, w)
        }
#pragma unroll
        for (int j = 0; j < HH; ++j) {
            const float4 lo = *(const float4*)(&h2buf[j][0]);
            const float4 hi = *(const float4*)(&h2buf[j][4]);
            const float w = whh1[j];
            FMA8(lo, hi, w)
        }
        *(float4*)(&gbuf[g][0]) = make_float4(acc[0], acc[1], acc[2], acc[3]);
        *(float4*)(&gbuf[g][4]) = make_float4(acc[4], acc[5], acc[6], acc[7]);
        __syncthreads();

        // ---- layer-1 state update ----
        {
            const float i0 = sig_(gbuf[ju][su]),          i1 = sig_(gbuf[ju][su + 1]);
            const float f0 = sig_(gbuf[HH + ju][su]),     f1 = sig_(gbuf[HH + ju][su + 1]);
            const float g0 = th_(gbuf[2 * HH + ju][su]),  g1 = th_(gbuf[2 * HH + ju][su + 1]);
            const float o0 = sig_(gbuf[3 * HH + ju][su]), o1 = sig_(gbuf[3 * HH + ju][su + 1]);
            c2a = f0 * c2a + i0 * g0;
            c2b = f1 * c2b + i1 * g1;
            h2buf[ju][su]     = o0 * th_(c2a);
            h2buf[ju][su + 1] = o1 * th_(c2b);
        }
        __syncthreads();   // new h2 visible (and gbuf reads done before next overwrite)
    }

    // ================= FC head on final h2 =================
    if (g < NS * 4) {
        const int s = g >> 2, k = g & 3;
        float a = fc_b[k];
#pragma unroll
        for (int j = 0; j < HH; ++j)
            a = fmaf(h2buf[j][s], fc_w[k * HH + j], a);
        out[(size_t)(s0 + s) * 4 + k] = a;
    }
}

extern "C" void kernel_launch(void* const* d_in, const int* in_sizes, int n_in,
                              void* d_out, int out_size, void* d_ws, size_t ws_size,
                              hipStream_t stream) {
    const float* x     = (const float*)d_in[0];
    const float* w_ih0 = (const float*)d_in[1];
    const float* w_hh0 = (const float*)d_in[2];
    const float* b_ih0 = (const float*)d_in[3];
    const float* b_hh0 = (const float*)d_in[4];
    const float* w_ih1 = (const float*)d_in[5];
    const float* w_hh1 = (const float*)d_in[6];
    const float* b_ih1 = (const float*)d_in[7];
    const float* b_hh1 = (const float*)d_in[8];
    const float* fc_w  = (const float*)d_in[9];
    const float* fc_b  = (const float*)d_in[10];
    float* out = (float*)d_out;

    dim3 grid(BB / NS), block(256);
    weather_lstm_fused<<<grid, block, 0, stream>>>(
        x, w_ih0, w_hh0, b_ih0, b_hh0,
        w_ih1, w_hh1, b_ih1, b_hh1, fc_w, fc_b, out);
}